// Round 13
// baseline (257.446 us; speedup 1.0000x reference)
//
#include <hip/hip_runtime.h>
#include <hip/hip_bf16.h>

typedef __attribute__((ext_vector_type(8))) __bf16 bf16x8;
typedef __attribute__((ext_vector_type(4))) float f32x4;

#define F_DIM 512
#define D_DIM 128
#define RPB 128            // rows per bucket (bucket = row >> 7)
#define MAXBUK 1024
#define BIN_CHUNK 8192
#define CAPMAX 3072        // >= runtime cap (2813); LDS sizing

__device__ __forceinline__ unsigned short f32_to_bf16_rn(float x) {
    union { float f; unsigned u; } v; v.f = x;
    unsigned u = v.u;
    unsigned rounded = u + 0x7fffu + ((u >> 16) & 1u);
    return (unsigned short)(rounded >> 16);
}
__device__ __forceinline__ float bf16_to_f32(unsigned short u) {
    return __uint_as_float((unsigned)u << 16);
}

// Wt transpose-convert only (cursor is hipMemsetAsync'ed)
__global__ void prep_kernel(const float* __restrict__ W, unsigned short* __restrict__ Wt) {
    int idx = blockIdx.x * 256 + threadIdx.x;   // 65536 total
    int n = idx >> 9;
    int k = idx & 511;
    Wt[idx] = f32_to_bf16_rn(W[k * D_DIM + n]);
}

// FUSED co-scheduled kernel: blocks [0, binBlocks) = edge binning;
// blocks [binBlocks, ...) = gemm.
// GEMM frame change: BK=256 fat-K stages, A-only LDS (32 KB, XOR-swizzled,
// single-buffered), B direct from L2-hot Wt with 1-step register prefetch.
// THREE raw-barrier sync points per block (vs 16 in all prior variants);
// stage-1 A-loads issued mid-compute-0 and kept in flight across the
// barrier (raw s_barrier + lgkmcnt(0) only -> no vmcnt drain).
__global__ __launch_bounds__(256) void fused_gemm_bin(
    const float* __restrict__ A, const unsigned short* __restrict__ Bt,
    unsigned short* __restrict__ Sb, int Nrows,
    const int* __restrict__ ei, const float* __restrict__ ev,
    int* __restrict__ cursor, uint2* __restrict__ ecv, int E, int nbuk,
    int cap, int binBlocks)
{
    __shared__ __align__(16) char smem[32768];
    const int tid = threadIdx.x;

    if ((int)blockIdx.x < binBlocks) {
        // ---------------- bin path (cursor starts zeroed) ----------------
        int* cnt = (int*)smem;
        int* bas = (int*)(smem + 4096);
        const int e0 = blockIdx.x * BIN_CHUNK;
        const int e1 = min(e0 + BIN_CHUNK, E);

        for (int i = tid; i < nbuk; i += 256) cnt[i] = 0;
        __syncthreads();
        for (int e = e0 + tid; e < e1; e += 256)
            atomicAdd(&cnt[ei[e] >> 7], 1);
        __syncthreads();
        for (int i = tid; i < nbuk; i += 256) {
            int c = cnt[i];
            bas[i] = c ? (i * cap + atomicAdd(&cursor[i], c)) : 0;
            cnt[i] = 0;
        }
        __syncthreads();
        for (int e = e0 + tid; e < e1; e += 256) {
            int r = ei[e];
            int b = r >> 7;
            int slot = atomicAdd(&cnt[b], 1);
            uint2 cv;
            cv.x = ((unsigned)ei[E + e] << 7) | (unsigned)(r & 127);
            cv.y = __float_as_uint(ev[e]);
            ecv[(size_t)bas[b] + slot] = cv;
        }
        return;
    }

    // ---------------- gemm path ----------------
    unsigned short* Aw = (unsigned short*)smem;   // [64 rows][256 bf16] = 32 KB

    const int gb   = blockIdx.x - binBlocks;
    const int wave = tid >> 6;
    const int lane = tid & 63;
    const int g    = lane >> 4;
    const int r16  = lane & 15;
    const int m0   = gb * 64;

    // staging role: thread covers row rt, k-quarter qt (64 f32 of the stage)
    const int rt = tid >> 2;
    const int qt = tid & 3;
    int arow = m0 + rt;
    if (arow >= Nrows) arow = Nrows - 1;          // duplicate-safe; stores guarded
    const float* aptr = A + (size_t)arow * F_DIM + qt * 64;

    float4 sa[16];                                 // staged A regs (static idx)
    auto loadStage = [&](int s) {
#pragma unroll
        for (int i = 0; i < 16; ++i)
            sa[i] = *(const float4*)(aptr + s * 256 + i * 4);
    };
    // convert + swizzled LDS write: chunk c = qt*8+j stored at c ^ (rt&15)
    auto storeStage = [&]() {
#pragma unroll
        for (int j = 0; j < 8; ++j) {
            union { uint4 q; __bf16 h[8]; } u;
            u.h[0]=(__bf16)sa[2*j].x;   u.h[1]=(__bf16)sa[2*j].y;
            u.h[2]=(__bf16)sa[2*j].z;   u.h[3]=(__bf16)sa[2*j].w;
            u.h[4]=(__bf16)sa[2*j+1].x; u.h[5]=(__bf16)sa[2*j+1].y;
            u.h[6]=(__bf16)sa[2*j+1].z; u.h[7]=(__bf16)sa[2*j+1].w;
            int c = qt * 8 + j;
            *(uint4*)(Aw + (size_t)rt * 256 + ((c ^ (rt & 15)) << 3)) = u.q;
        }
    };

    // B: direct from Wt with one-step register prefetch
    const unsigned short* bb = Bt + (size_t)r16 * F_DIM + g * 8;
    bf16x8 bcur[8], bnext[8];
    auto loadB = [&](bf16x8* dst, int kg) {
#pragma unroll
        for (int nf = 0; nf < 8; ++nf)
            dst[nf] = *(const bf16x8*)(bb + (size_t)nf * 16 * F_DIM + kg * 32);
    };

    const unsigned short* Ar = Aw + (size_t)(wave * 16 + r16) * 256;

    f32x4 acc[8];
#pragma unroll
    for (int j = 0; j < 8; ++j) acc[j] = (f32x4)0.0f;

    // prologue: stage 0
    loadStage(0);
    loadB(bcur, 0);
    storeStage();
    asm volatile("s_waitcnt lgkmcnt(0)" ::: "memory");
    __builtin_amdgcn_s_barrier();

    // compute stage 0 (k-steps 0..7), stage-1 A-loads issued at ks==3
#pragma unroll
    for (int ks = 0; ks < 8; ++ks) {
        if (ks == 3) loadStage(1);                // in flight across the barrier
        loadB(bnext, ks + 1);
        bf16x8 af = *(const bf16x8*)(Ar + (((ks * 4 + g) ^ r16) << 3));
#pragma unroll
        for (int nf = 0; nf < 8; ++nf)
            acc[nf] = __builtin_amdgcn_mfma_f32_16x16x32_bf16(af, bcur[nf], acc[nf], 0, 0, 0);
#pragma unroll
        for (int nf = 0; nf < 8; ++nf) bcur[nf] = bnext[nf];
    }
    asm volatile("s_waitcnt lgkmcnt(0)" ::: "memory");   // stage-0 reads retired
    __builtin_amdgcn_s_barrier();
    storeStage();                                  // counted vmcnt on sa, not 0
    asm volatile("s_waitcnt lgkmcnt(0)" ::: "memory");
    __builtin_amdgcn_s_barrier();

    // compute stage 1 (k-steps 8..15)
#pragma unroll
    for (int ks = 0; ks < 8; ++ks) {
        const int kg = 8 + ks;
        if (kg < 15) loadB(bnext, kg + 1);
        bf16x8 af = *(const bf16x8*)(Ar + (((ks * 4 + g) ^ r16) << 3));
#pragma unroll
        for (int nf = 0; nf < 8; ++nf)
            acc[nf] = __builtin_amdgcn_mfma_f32_16x16x32_bf16(af, bcur[nf], acc[nf], 0, 0, 0);
        if (kg < 15) {
#pragma unroll
            for (int nf = 0; nf < 8; ++nf) bcur[nf] = bnext[nf];
        }
    }

    // epilogue: relu + bf16 store
#pragma unroll
    for (int nf = 0; nf < 8; ++nf) {
#pragma unroll
        for (int r = 0; r < 4; ++r) {
            int row = m0 + wave * 16 + g * 4 + r;
            if (row < Nrows) {
                float v = acc[nf][r];
                Sb[(size_t)row * D_DIM + nf * 16 + r16] = f32_to_bf16_rn(v > 0.f ? v : 0.f);
            }
        }
    }
}

// FUSED sort+accumulate: one block per bucket, 512 threads, 8 waves.
// LDS counting-sort by local row, then each wave owns 16 rows processed in
// PAIRS over their merged (contiguous) sorted range: 8-deep unrolled gather
// loop with branchless mask-select into the two accumulator pairs.
__global__ __launch_bounds__(512) void sortaccum_kernel(
    const uint2* __restrict__ ecv, const int* __restrict__ cursor,
    const unsigned short* __restrict__ Sb, const float* __restrict__ bias,
    float* __restrict__ out, int Nrows, int cap)
{
    __shared__ uint2 raw[CAPMAX];   // 24 KB
    __shared__ uint2 srt[CAPMAX];   // 24 KB
    __shared__ int cnt[RPB];
    __shared__ int base[RPB];
    __shared__ int scur[RPB];

    const int tid = threadIdx.x;
    const int b   = blockIdx.x;
    const int beg = b * cap;
    int n = cursor[b];                    // count (cursor started at 0)
    if (n > cap) n = cap;

    if (tid < RPB) cnt[tid] = 0;
    __syncthreads();
    for (int i = tid; i < n; i += 512) {
        uint2 cv = ecv[beg + i];
        raw[i] = cv;
        atomicAdd(&cnt[cv.x & 127], 1);
    }
    __syncthreads();
    if (tid < 64) {
        int carry = 0;
#pragma unroll
        for (int c = 0; c < 2; ++c) {
            int idx = c * 64 + tid;
            int v = cnt[idx];
            int orig = v;
            for (int d = 1; d < 64; d <<= 1) {
                int t = __shfl_up(v, d, 64);
                if (tid >= d) v += t;
            }
            int excl = carry + v - orig;
            base[idx] = excl;
            scur[idx] = excl;
            carry += __shfl(v, 63, 64);
        }
    }
    __syncthreads();
    for (int i = tid; i < n; i += 512) {
        uint2 cv = raw[i];
        int slot = atomicAdd(&scur[cv.x & 127], 1);
        srt[slot] = cv;
    }
    __syncthreads();

    const int wv   = tid >> 6;
    const int lane = tid & 63;
    const int c2   = lane * 2;
    const int r0g  = b * RPB;

#define GATHER(J) \
    uint2 cv##J = srt[i + J]; \
    ushort2 sv##J = *(const ushort2*)&Sb[(size_t)(cv##J.x >> 7) * D_DIM + c2];

#define ACCUM(J) { \
    float v = __uint_as_float(cv##J.y); \
    float sel = ((int)(cv##J.x & 127) == rl0) ? 1.f : 0.f; \
    float px = v * bf16_to_f32(sv##J.x); \
    float py = v * bf16_to_f32(sv##J.y); \
    ax0 += sel * px; ay0 += sel * py; \
    ax1 += px - sel * px; ay1 += py - sel * py; }

    for (int rr = 0; rr < 16; rr += 2) {
        const int rl0 = wv * 16 + rr;
        const int s  = base[rl0];
        const int e  = s + cnt[rl0] + cnt[rl0 + 1];

        float ax0 = 0.f, ay0 = 0.f, ax1 = 0.f, ay1 = 0.f;
        int i = s;
        for (; i + 7 < e; i += 8) {
            GATHER(0) GATHER(1) GATHER(2) GATHER(3)
            GATHER(4) GATHER(5) GATHER(6) GATHER(7)
            ACCUM(0) ACCUM(1) ACCUM(2) ACCUM(3)
            ACCUM(4) ACCUM(5) ACCUM(6) ACCUM(7)
        }
        for (; i < e; ++i) {
            GATHER(0)
            ACCUM(0)
        }

        int row0 = r0g + rl0;
        if (row0 < Nrows) {
            ushort2 so = *(const ushort2*)&Sb[(size_t)row0 * D_DIM + c2];
            float2 bv = *(const float2*)&bias[c2];
            float2 o;
            o.x = ax0 + bf16_to_f32(so.x) + bv.x;
            o.y = ay0 + bf16_to_f32(so.y) + bv.y;
            *(float2*)&out[(size_t)row0 * D_DIM + c2] = o;
        }
        int row1 = row0 + 1;
        if (row1 < Nrows) {
            ushort2 so = *(const ushort2*)&Sb[(size_t)row1 * D_DIM + c2];
            float2 bv = *(const float2*)&bias[c2];
            float2 o;
            o.x = ax1 + bf16_to_f32(so.x) + bv.x;
            o.y = ay1 + bf16_to_f32(so.y) + bv.y;
            *(float2*)&out[(size_t)row1 * D_DIM + c2] = o;
        }
    }
#undef GATHER
#undef ACCUM
}

extern "C" void kernel_launch(void* const* d_in, const int* in_sizes, int n_in,
                              void* d_out, int out_size, void* d_ws, size_t ws_size,
                              hipStream_t stream) {
    const float* feature = (const float*)d_in[0];
    const float* W       = (const float*)d_in[1];
    const float* bias    = (const float*)d_in[2];
    const float* ev      = (const float*)d_in[3];
    const int*   ei      = (const int*)d_in[4];
    float* out = (float*)d_out;

    const int N = in_sizes[0] / F_DIM;   // 100000
    const int E = in_sizes[3];           // 1600000
    const int nbuk = (N + RPB - 1) / RPB;            // 782
    int cap = (E + nbuk - 1) / nbuk;
    cap = cap + cap / 4 + 256;                       // ~2813 (<= CAPMAX)
    if (cap > CAPMAX) cap = CAPMAX;

    char* ws = (char*)d_ws;
    size_t cur = 0;
    auto alloc = [&](size_t bytes) -> void* {
        void* p = ws + cur;
        cur = (cur + bytes + 255) & ~(size_t)255;
        return p;
    };
    unsigned short* Sb     = (unsigned short*)alloc((size_t)N * D_DIM * 2);
    unsigned short* Wt     = (unsigned short*)alloc((size_t)D_DIM * F_DIM * 2);
    int*            cursor = (int*)alloc((size_t)nbuk * 4);
    uint2*          ecv    = (uint2*)alloc(((size_t)nbuk * cap + BIN_CHUNK) * 8);
    (void)ws_size;

    const int binBlocks  = (E + BIN_CHUNK - 1) / BIN_CHUNK;   // 196
    const int gemmBlocks = (N + 63) / 64;                     // 1563

    hipMemsetAsync(cursor, 0, (size_t)nbuk * 4, stream);
    prep_kernel<<<256, 256, 0, stream>>>(W, Wt);
    fused_gemm_bin<<<binBlocks + gemmBlocks, 256, 0, stream>>>(
        feature, Wt, Sb, N, ei, ev, cursor, ecv, E, nbuk, cap, binBlocks);
    sortaccum_kernel<<<nbuk, 512, 0, stream>>>(ecv, cursor, Sb, bias, out, N, cap);
}

// Round 14
// 207.171 us; speedup vs baseline: 1.2427x; 1.2427x over previous
//
#include <hip/hip_runtime.h>
#include <hip/hip_bf16.h>

typedef __attribute__((ext_vector_type(8))) __bf16 bf16x8;
typedef __attribute__((ext_vector_type(4))) float f32x4;

#define F_DIM 512
#define D_DIM 128
#define RPB 128            // rows per bucket (bucket = row >> 7)
#define MAXBUK 1024
#define BIN_CHUNK 8192
#define CAPMAX 3072        // >= runtime cap (2813); LDS sizing

__device__ __forceinline__ unsigned short f32_to_bf16_rn(float x) {
    union { float f; unsigned u; } v; v.f = x;
    unsigned u = v.u;
    unsigned rounded = u + 0x7fffu + ((u >> 16) & 1u);
    return (unsigned short)(rounded >> 16);
}
__device__ __forceinline__ float bf16_to_f32(unsigned short u) {
    return __uint_as_float((unsigned)u << 16);
}

// Wt transpose-convert only (cursor is hipMemsetAsync'ed)
__global__ void prep_kernel(const float* __restrict__ W, unsigned short* __restrict__ Wt) {
    int idx = blockIdx.x * 256 + threadIdx.x;   // 65536 total
    int n = idx >> 9;
    int k = idx & 511;
    Wt[idx] = f32_to_bf16_rn(W[k * D_DIM + n]);
}

// FUSED co-scheduled kernel: blocks [0, binBlocks) = edge binning;
// blocks [binBlocks, ...) = gemm.
// GEMM: 64(M) x 64(N) tile (grid x2: gb = stripe*2 + colhalf, pair-adjacent
// so the A re-read by the second half is L2/L3-hot), BK=32, 4 waves,
// reg-staged + LDS double-buffer, one barrier per K-step.
// LDS = 20 480 B -> 8 blocks/CU (32 waves, 100% LDS-side cap); acc = 16 VGPR.
// The ONLY change vs the 133-us R12 version is the resident-wave count:
// occupancy is the one lever that has moved this latency-bound phase.
__global__ __launch_bounds__(256, 6) void fused_gemm_bin(
    const float* __restrict__ A, const unsigned short* __restrict__ Bt,
    unsigned short* __restrict__ Sb, int Nrows,
    const int* __restrict__ ei, const float* __restrict__ ev,
    int* __restrict__ cursor, uint2* __restrict__ ecv, int E, int nbuk,
    int cap, int binBlocks)
{
    __shared__ __align__(16) char smem[20480];
    const int tid = threadIdx.x;

    if ((int)blockIdx.x < binBlocks) {
        // ---------------- bin path (cursor starts zeroed) ----------------
        int* cnt = (int*)smem;                 // nbuk ints (<= 4096 B)
        int* bas = (int*)(smem + 4096);        // nbuk ints
        const int e0 = blockIdx.x * BIN_CHUNK;
        const int e1 = min(e0 + BIN_CHUNK, E);

        for (int i = tid; i < nbuk; i += 256) cnt[i] = 0;
        __syncthreads();
        for (int e = e0 + tid; e < e1; e += 256)
            atomicAdd(&cnt[ei[e] >> 7], 1);
        __syncthreads();
        for (int i = tid; i < nbuk; i += 256) {
            int c = cnt[i];
            bas[i] = c ? (i * cap + atomicAdd(&cursor[i], c)) : 0;
            cnt[i] = 0;
        }
        __syncthreads();
        for (int e = e0 + tid; e < e1; e += 256) {
            int r = ei[e];
            int b = r >> 7;
            int slot = atomicAdd(&cnt[b], 1);
            uint2 cv;
            cv.x = ((unsigned)ei[E + e] << 7) | (unsigned)(r & 127);
            cv.y = __float_as_uint(ev[e]);
            ecv[(size_t)bas[b] + slot] = cv;
        }
        return;
    }

    // ---------------- gemm path (64x64 tile) ----------------
    unsigned short* Al = (unsigned short*)smem;            // 2*64*40 = 10240 B
    unsigned short* Bl = (unsigned short*)(smem + 10240);  // 2*64*40 = 10240 B

    const int gb     = blockIdx.x - binBlocks;
    const int stripe = gb >> 1;
    const int half   = gb & 1;
    const int wave = tid >> 6;
    const int lane = tid & 63;
    const int g    = lane >> 4;
    const int r16  = lane & 15;
    const int m0   = stripe * 64;
    const int n0   = half * 64;

    // A staging: thread covers row sar (0..63), k-quarter skq (8 f32 = 32 B)
    const int sar = tid >> 2;
    const int skq = tid & 3;
    int arow = m0 + sar;
    if (arow >= Nrows) arow = Nrows - 1;       // duplicate-safe; stores guarded
    const float* aptr = A + (size_t)arow * F_DIM + skq * 8;
    const int awoff = sar * 40 + skq * 8;

    // B staging: thread covers Wt row n0+sbn (0..63), k-eighth skb (8 bf16 = 16 B)
    const int sbn = tid >> 2;
    const int skb = (tid & 3) * 8;
    const unsigned short* bptr = Bt + (size_t)(n0 + sbn) * F_DIM + skb;
    const int bwoff = sbn * 40 + skb;

    float4 ar0, ar1;
    uint4  br0;

    auto loadAB = [&](int ks) {
        const float4* pa = (const float4*)(aptr + ks * 32);
        ar0 = pa[0]; ar1 = pa[1];
        br0 = *(const uint4*)(bptr + ks * 32);
    };
    auto storeAB = [&](int buf) {
        union { uint4 q; __bf16 h[8]; } u;
        u.h[0]=(__bf16)ar0.x; u.h[1]=(__bf16)ar0.y; u.h[2]=(__bf16)ar0.z; u.h[3]=(__bf16)ar0.w;
        u.h[4]=(__bf16)ar1.x; u.h[5]=(__bf16)ar1.y; u.h[6]=(__bf16)ar1.z; u.h[7]=(__bf16)ar1.w;
        *(uint4*)&Al[buf * 2560 + awoff] = u.q;
        *(uint4*)&Bl[buf * 2560 + bwoff] = br0;
    };

    f32x4 acc[4];
#pragma unroll
    for (int j = 0; j < 4; ++j) acc[j] = (f32x4)0.0f;

    loadAB(0);
    storeAB(0);
    __syncthreads();

#pragma unroll
    for (int ks = 0; ks < 16; ++ks) {
        const int cur = ks & 1;
        if (ks < 15) loadAB(ks + 1);

        const unsigned short* Ab = Al + cur * 2560;
        const unsigned short* Bb = Bl + cur * 2560;
        bf16x8 af = *(const bf16x8*)&Ab[(wave * 16 + r16) * 40 + g * 8];
#pragma unroll
        for (int nf = 0; nf < 4; ++nf) {
            bf16x8 bf = *(const bf16x8*)&Bb[(nf * 16 + r16) * 40 + g * 8];
            acc[nf] = __builtin_amdgcn_mfma_f32_16x16x32_bf16(af, bf, acc[nf], 0, 0, 0);
        }

        if (ks < 15) storeAB(cur ^ 1);
        __syncthreads();
    }

#pragma unroll
    for (int nf = 0; nf < 4; ++nf) {
#pragma unroll
        for (int r = 0; r < 4; ++r) {
            int row = m0 + wave * 16 + g * 4 + r;
            if (row < Nrows) {
                float v = acc[nf][r];
                Sb[(size_t)row * D_DIM + n0 + nf * 16 + r16] = f32_to_bf16_rn(v > 0.f ? v : 0.f);
            }
        }
    }
}

// FUSED sort+accumulate: one block per bucket, 512 threads, 8 waves.
// LDS counting-sort by local row, then each wave owns 16 rows processed in
// PAIRS over their merged (contiguous) sorted range: 8-deep unrolled gather
// loop with branchless mask-select into the two accumulator pairs.
__global__ __launch_bounds__(512) void sortaccum_kernel(
    const uint2* __restrict__ ecv, const int* __restrict__ cursor,
    const unsigned short* __restrict__ Sb, const float* __restrict__ bias,
    float* __restrict__ out, int Nrows, int cap)
{
    __shared__ uint2 raw[CAPMAX];   // 24 KB
    __shared__ uint2 srt[CAPMAX];   // 24 KB
    __shared__ int cnt[RPB];
    __shared__ int base[RPB];
    __shared__ int scur[RPB];

    const int tid = threadIdx.x;
    const int b   = blockIdx.x;
    const int beg = b * cap;
    int n = cursor[b];                    // count (cursor started at 0)
    if (n > cap) n = cap;

    if (tid < RPB) cnt[tid] = 0;
    __syncthreads();
    for (int i = tid; i < n; i += 512) {
        uint2 cv = ecv[beg + i];
        raw[i] = cv;
        atomicAdd(&cnt[cv.x & 127], 1);
    }
    __syncthreads();
    if (tid < 64) {
        int carry = 0;
#pragma unroll
        for (int c = 0; c < 2; ++c) {
            int idx = c * 64 + tid;
            int v = cnt[idx];
            int orig = v;
            for (int d = 1; d < 64; d <<= 1) {
                int t = __shfl_up(v, d, 64);
                if (tid >= d) v += t;
            }
            int excl = carry + v - orig;
            base[idx] = excl;
            scur[idx] = excl;
            carry += __shfl(v, 63, 64);
        }
    }
    __syncthreads();
    for (int i = tid; i < n; i += 512) {
        uint2 cv = raw[i];
        int slot = atomicAdd(&scur[cv.x & 127], 1);
        srt[slot] = cv;
    }
    __syncthreads();

    const int wv   = tid >> 6;
    const int lane = tid & 63;
    const int c2   = lane * 2;
    const int r0g  = b * RPB;

#define GATHER(J) \
    uint2 cv##J = srt[i + J]; \
    ushort2 sv##J = *(const ushort2*)&Sb[(size_t)(cv##J.x >> 7) * D_DIM + c2];

#define ACCUM(J) { \
    float v = __uint_as_float(cv##J.y); \
    float sel = ((int)(cv##J.x & 127) == rl0) ? 1.f : 0.f; \
    float px = v * bf16_to_f32(sv##J.x); \
    float py = v * bf16_to_f32(sv##J.y); \
    ax0 += sel * px; ay0 += sel * py; \
    ax1 += px - sel * px; ay1 += py - sel * py; }

    for (int rr = 0; rr < 16; rr += 2) {
        const int rl0 = wv * 16 + rr;
        const int s  = base[rl0];
        const int e  = s + cnt[rl0] + cnt[rl0 + 1];

        float ax0 = 0.f, ay0 = 0.f, ax1 = 0.f, ay1 = 0.f;
        int i = s;
        for (; i + 7 < e; i += 8) {
            GATHER(0) GATHER(1) GATHER(2) GATHER(3)
            GATHER(4) GATHER(5) GATHER(6) GATHER(7)
            ACCUM(0) ACCUM(1) ACCUM(2) ACCUM(3)
            ACCUM(4) ACCUM(5) ACCUM(6) ACCUM(7)
        }
        for (; i < e; ++i) {
            GATHER(0)
            ACCUM(0)
        }

        int row0 = r0g + rl0;
        if (row0 < Nrows) {
            ushort2 so = *(const ushort2*)&Sb[(size_t)row0 * D_DIM + c2];
            float2 bv = *(const float2*)&bias[c2];
            float2 o;
            o.x = ax0 + bf16_to_f32(so.x) + bv.x;
            o.y = ay0 + bf16_to_f32(so.y) + bv.y;
            *(float2*)&out[(size_t)row0 * D_DIM + c2] = o;
        }
        int row1 = row0 + 1;
        if (row1 < Nrows) {
            ushort2 so = *(const ushort2*)&Sb[(size_t)row1 * D_DIM + c2];
            float2 bv = *(const float2*)&bias[c2];
            float2 o;
            o.x = ax1 + bf16_to_f32(so.x) + bv.x;
            o.y = ay1 + bf16_to_f32(so.y) + bv.y;
            *(float2*)&out[(size_t)row1 * D_DIM + c2] = o;
        }
    }
#undef GATHER
#undef ACCUM
}

extern "C" void kernel_launch(void* const* d_in, const int* in_sizes, int n_in,
                              void* d_out, int out_size, void* d_ws, size_t ws_size,
                              hipStream_t stream) {
    const float* feature = (const float*)d_in[0];
    const float* W       = (const float*)d_in[1];
    const float* bias    = (const float*)d_in[2];
    const float* ev      = (const float*)d_in[3];
    const int*   ei      = (const int*)d_in[4];
    float* out = (float*)d_out;

    const int N = in_sizes[0] / F_DIM;   // 100000
    const int E = in_sizes[3];           // 1600000
    const int nbuk = (N + RPB - 1) / RPB;            // 782
    int cap = (E + nbuk - 1) / nbuk;
    cap = cap + cap / 4 + 256;                       // ~2813 (<= CAPMAX)
    if (cap > CAPMAX) cap = CAPMAX;

    char* ws = (char*)d_ws;
    size_t cur = 0;
    auto alloc = [&](size_t bytes) -> void* {
        void* p = ws + cur;
        cur = (cur + bytes + 255) & ~(size_t)255;
        return p;
    };
    unsigned short* Sb     = (unsigned short*)alloc((size_t)N * D_DIM * 2);
    unsigned short* Wt     = (unsigned short*)alloc((size_t)D_DIM * F_DIM * 2);
    int*            cursor = (int*)alloc((size_t)nbuk * 4);
    uint2*          ecv    = (uint2*)alloc(((size_t)nbuk * cap + BIN_CHUNK) * 8);
    (void)ws_size;

    const int binBlocks  = (E + BIN_CHUNK - 1) / BIN_CHUNK;   // 196
    const int gemmBlocks = 2 * ((N + 63) / 64);               // 3126

    hipMemsetAsync(cursor, 0, (size_t)nbuk * 4, stream);
    prep_kernel<<<256, 256, 0, stream>>>(W, Wt);
    fused_gemm_bin<<<binBlocks + gemmBlocks, 256, 0, stream>>>(
        feature, Wt, Sb, N, ei, ev, cursor, ecv, E, nbuk, cap, binBlocks);
    sortaccum_kernel<<<nbuk, 512, 0, stream>>>(ecv, cursor, Sb, bias, out, N, cap);
}

// Round 15
// 202.386 us; speedup vs baseline: 1.2721x; 1.0236x over previous
//
#include <hip/hip_runtime.h>
#include <hip/hip_bf16.h>

typedef __attribute__((ext_vector_type(8))) __bf16 bf16x8;
typedef __attribute__((ext_vector_type(4))) float f32x4;

#define F_DIM 512
#define D_DIM 128
#define RPB 128            // rows per bucket (bucket = row >> 7)
#define MAXBUK 1024
#define BIN_CHUNK 8192
#define CAPMAX 3072        // >= runtime cap (2813); LDS sizing

__device__ __forceinline__ unsigned short f32_to_bf16_rn(float x) {
    union { float f; unsigned u; } v; v.f = x;
    unsigned u = v.u;
    unsigned rounded = u + 0x7fffu + ((u >> 16) & 1u);
    return (unsigned short)(rounded >> 16);
}
__device__ __forceinline__ float bf16_to_f32(unsigned short u) {
    return __uint_as_float((unsigned)u << 16);
}

// Wt transpose-convert only (cursor is hipMemsetAsync'ed)
__global__ void prep_kernel(const float* __restrict__ W, unsigned short* __restrict__ Wt) {
    int idx = blockIdx.x * 256 + threadIdx.x;   // 65536 total
    int n = idx >> 9;
    int k = idx & 511;
    Wt[idx] = f32_to_bf16_rn(W[k * D_DIM + n]);
}

// FUSED co-scheduled kernel: blocks [0, binBlocks) = edge binning;
// blocks [binBlocks, ...) = gemm.
// GEMM: 64(M) x 64(N) tile, BK=32, 4 waves, reg-staged + LDS double-buffer,
// one barrier per K-step, 20 480 B LDS -> 8 blocks/CU (R14's 62% occupancy).
// NEW vs R14: XCD-aware pair mapping. The two col-half blocks that share an
// A stripe are placed 8 blockIdx apart -> same (b%8) XCD -> the second
// block's A read hits that XCD's private L2 instead of re-fetching HBM
// (R14 paired them adjacently -> different XCDs -> +100 MB FETCH).
__global__ __launch_bounds__(256, 6) void fused_gemm_bin(
    const float* __restrict__ A, const unsigned short* __restrict__ Bt,
    unsigned short* __restrict__ Sb, int Nrows,
    const int* __restrict__ ei, const float* __restrict__ ev,
    int* __restrict__ cursor, uint2* __restrict__ ecv, int E, int nbuk,
    int cap, int binBlocks)
{
    __shared__ __align__(16) char smem[20480];
    const int tid = threadIdx.x;

    if ((int)blockIdx.x < binBlocks) {
        // ---------------- bin path (cursor starts zeroed) ----------------
        int* cnt = (int*)smem;                 // nbuk ints (<= 4096 B)
        int* bas = (int*)(smem + 4096);        // nbuk ints
        const int e0 = blockIdx.x * BIN_CHUNK;
        const int e1 = min(e0 + BIN_CHUNK, E);

        for (int i = tid; i < nbuk; i += 256) cnt[i] = 0;
        __syncthreads();
        for (int e = e0 + tid; e < e1; e += 256)
            atomicAdd(&cnt[ei[e] >> 7], 1);
        __syncthreads();
        for (int i = tid; i < nbuk; i += 256) {
            int c = cnt[i];
            bas[i] = c ? (i * cap + atomicAdd(&cursor[i], c)) : 0;
            cnt[i] = 0;
        }
        __syncthreads();
        for (int e = e0 + tid; e < e1; e += 256) {
            int r = ei[e];
            int b = r >> 7;
            int slot = atomicAdd(&cnt[b], 1);
            uint2 cv;
            cv.x = ((unsigned)ei[E + e] << 7) | (unsigned)(r & 127);
            cv.y = __float_as_uint(ev[e]);
            ecv[(size_t)bas[b] + slot] = cv;
        }
        return;
    }

    // ---------------- gemm path (64x64 tile, XCD-paired) ----------------
    unsigned short* Al = (unsigned short*)smem;            // 2*64*40 = 10240 B
    unsigned short* Bl = (unsigned short*)(smem + 10240);  // 2*64*40 = 10240 B

    const int gb     = blockIdx.x - binBlocks;
    // pair mapping: gb and gb+8 share a stripe and the same XCD (b%8 equal)
    const int grp    = gb >> 4;
    const int stripe = grp * 8 + (gb & 7);
    const int half   = (gb >> 3) & 1;
    const int m0   = stripe * 64;
    if (m0 >= Nrows) return;                   // grid rounded up to x16
    const int n0   = half * 64;

    const int wave = tid >> 6;
    const int lane = tid & 63;
    const int g    = lane >> 4;
    const int r16  = lane & 15;

    // A staging: thread covers row sar (0..63), k-quarter skq (8 f32 = 32 B)
    const int sar = tid >> 2;
    const int skq = tid & 3;
    int arow = m0 + sar;
    if (arow >= Nrows) arow = Nrows - 1;       // duplicate-safe; stores guarded
    const float* aptr = A + (size_t)arow * F_DIM + skq * 8;
    const int awoff = sar * 40 + skq * 8;

    // B staging: thread covers Wt row n0+sbn (0..63), k-eighth skb (8 bf16 = 16 B)
    const int sbn = tid >> 2;
    const int skb = (tid & 3) * 8;
    const unsigned short* bptr = Bt + (size_t)(n0 + sbn) * F_DIM + skb;
    const int bwoff = sbn * 40 + skb;

    float4 ar0, ar1;
    uint4  br0;

    auto loadAB = [&](int ks) {
        const float4* pa = (const float4*)(aptr + ks * 32);
        ar0 = pa[0]; ar1 = pa[1];
        br0 = *(const uint4*)(bptr + ks * 32);
    };
    auto storeAB = [&](int buf) {
        union { uint4 q; __bf16 h[8]; } u;
        u.h[0]=(__bf16)ar0.x; u.h[1]=(__bf16)ar0.y; u.h[2]=(__bf16)ar0.z; u.h[3]=(__bf16)ar0.w;
        u.h[4]=(__bf16)ar1.x; u.h[5]=(__bf16)ar1.y; u.h[6]=(__bf16)ar1.z; u.h[7]=(__bf16)ar1.w;
        *(uint4*)&Al[buf * 2560 + awoff] = u.q;
        *(uint4*)&Bl[buf * 2560 + bwoff] = br0;
    };

    f32x4 acc[4];
#pragma unroll
    for (int j = 0; j < 4; ++j) acc[j] = (f32x4)0.0f;

    loadAB(0);
    storeAB(0);
    __syncthreads();

#pragma unroll
    for (int ks = 0; ks < 16; ++ks) {
        const int cur = ks & 1;
        if (ks < 15) loadAB(ks + 1);

        const unsigned short* Ab = Al + cur * 2560;
        const unsigned short* Bb = Bl + cur * 2560;
        bf16x8 af = *(const bf16x8*)&Ab[(wave * 16 + r16) * 40 + g * 8];
#pragma unroll
        for (int nf = 0; nf < 4; ++nf) {
            bf16x8 bf = *(const bf16x8*)&Bb[(nf * 16 + r16) * 40 + g * 8];
            acc[nf] = __builtin_amdgcn_mfma_f32_16x16x32_bf16(af, bf, acc[nf], 0, 0, 0);
        }

        if (ks < 15) storeAB(cur ^ 1);
        __syncthreads();
    }

#pragma unroll
    for (int nf = 0; nf < 4; ++nf) {
#pragma unroll
        for (int r = 0; r < 4; ++r) {
            int row = m0 + wave * 16 + g * 4 + r;
            if (row < Nrows) {
                float v = acc[nf][r];
                Sb[(size_t)row * D_DIM + n0 + nf * 16 + r16] = f32_to_bf16_rn(v > 0.f ? v : 0.f);
            }
        }
    }
}

// FUSED sort+accumulate: one block per bucket, 512 threads, 8 waves.
// LDS counting-sort by local row, then each wave owns 16 rows processed in
// PAIRS over their merged (contiguous) sorted range: 8-deep unrolled gather
// loop with branchless mask-select into the two accumulator pairs.
__global__ __launch_bounds__(512) void sortaccum_kernel(
    const uint2* __restrict__ ecv, const int* __restrict__ cursor,
    const unsigned short* __restrict__ Sb, const float* __restrict__ bias,
    float* __restrict__ out, int Nrows, int cap)
{
    __shared__ uint2 raw[CAPMAX];   // 24 KB
    __shared__ uint2 srt[CAPMAX];   // 24 KB
    __shared__ int cnt[RPB];
    __shared__ int base[RPB];
    __shared__ int scur[RPB];

    const int tid = threadIdx.x;
    const int b   = blockIdx.x;
    const int beg = b * cap;
    int n = cursor[b];                    // count (cursor started at 0)
    if (n > cap) n = cap;

    if (tid < RPB) cnt[tid] = 0;
    __syncthreads();
    for (int i = tid; i < n; i += 512) {
        uint2 cv = ecv[beg + i];
        raw[i] = cv;
        atomicAdd(&cnt[cv.x & 127], 1);
    }
    __syncthreads();
    if (tid < 64) {
        int carry = 0;
#pragma unroll
        for (int c = 0; c < 2; ++c) {
            int idx = c * 64 + tid;
            int v = cnt[idx];
            int orig = v;
            for (int d = 1; d < 64; d <<= 1) {
                int t = __shfl_up(v, d, 64);
                if (tid >= d) v += t;
            }
            int excl = carry + v - orig;
            base[idx] = excl;
            scur[idx] = excl;
            carry += __shfl(v, 63, 64);
        }
    }
    __syncthreads();
    for (int i = tid; i < n; i += 512) {
        uint2 cv = raw[i];
        int slot = atomicAdd(&scur[cv.x & 127], 1);
        srt[slot] = cv;
    }
    __syncthreads();

    const int wv   = tid >> 6;
    const int lane = tid & 63;
    const int c2   = lane * 2;
    const int r0g  = b * RPB;

#define GATHER(J) \
    uint2 cv##J = srt[i + J]; \
    ushort2 sv##J = *(const ushort2*)&Sb[(size_t)(cv##J.x >> 7) * D_DIM + c2];

#define ACCUM(J) { \
    float v = __uint_as_float(cv##J.y); \
    float sel = ((int)(cv##J.x & 127) == rl0) ? 1.f : 0.f; \
    float px = v * bf16_to_f32(sv##J.x); \
    float py = v * bf16_to_f32(sv##J.y); \
    ax0 += sel * px; ay0 += sel * py; \
    ax1 += px - sel * px; ay1 += py - sel * py; }

    for (int rr = 0; rr < 16; rr += 2) {
        const int rl0 = wv * 16 + rr;
        const int s  = base[rl0];
        const int e  = s + cnt[rl0] + cnt[rl0 + 1];

        float ax0 = 0.f, ay0 = 0.f, ax1 = 0.f, ay1 = 0.f;
        int i = s;
        for (; i + 7 < e; i += 8) {
            GATHER(0) GATHER(1) GATHER(2) GATHER(3)
            GATHER(4) GATHER(5) GATHER(6) GATHER(7)
            ACCUM(0) ACCUM(1) ACCUM(2) ACCUM(3)
            ACCUM(4) ACCUM(5) ACCUM(6) ACCUM(7)
        }
        for (; i < e; ++i) {
            GATHER(0)
            ACCUM(0)
        }

        int row0 = r0g + rl0;
        if (row0 < Nrows) {
            ushort2 so = *(const ushort2*)&Sb[(size_t)row0 * D_DIM + c2];
            float2 bv = *(const float2*)&bias[c2];
            float2 o;
            o.x = ax0 + bf16_to_f32(so.x) + bv.x;
            o.y = ay0 + bf16_to_f32(so.y) + bv.y;
            *(float2*)&out[(size_t)row0 * D_DIM + c2] = o;
        }
        int row1 = row0 + 1;
        if (row1 < Nrows) {
            ushort2 so = *(const ushort2*)&Sb[(size_t)row1 * D_DIM + c2];
            float2 bv = *(const float2*)&bias[c2];
            float2 o;
            o.x = ax1 + bf16_to_f32(so.x) + bv.x;
            o.y = ay1 + bf16_to_f32(so.y) + bv.y;
            *(float2*)&out[(size_t)row1 * D_DIM + c2] = o;
        }
    }
#undef GATHER
#undef ACCUM
}

extern "C" void kernel_launch(void* const* d_in, const int* in_sizes, int n_in,
                              void* d_out, int out_size, void* d_ws, size_t ws_size,
                              hipStream_t stream) {
    const float* feature = (const float*)d_in[0];
    const float* W       = (const float*)d_in[1];
    const float* bias    = (const float*)d_in[2];
    const float* ev      = (const float*)d_in[3];
    const int*   ei      = (const int*)d_in[4];
    float* out = (float*)d_out;

    const int N = in_sizes[0] / F_DIM;   // 100000
    const int E = in_sizes[3];           // 1600000
    const int nbuk = (N + RPB - 1) / RPB;            // 782
    int cap = (E + nbuk - 1) / nbuk;
    cap = cap + cap / 4 + 256;                       // ~2813 (<= CAPMAX)
    if (cap > CAPMAX) cap = CAPMAX;

    char* ws = (char*)d_ws;
    size_t cur = 0;
    auto alloc = [&](size_t bytes) -> void* {
        void* p = ws + cur;
        cur = (cur + bytes + 255) & ~(size_t)255;
        return p;
    };
    unsigned short* Sb     = (unsigned short*)alloc((size_t)N * D_DIM * 2);
    unsigned short* Wt     = (unsigned short*)alloc((size_t)D_DIM * F_DIM * 2);
    int*            cursor = (int*)alloc((size_t)nbuk * 4);
    uint2*          ecv    = (uint2*)alloc(((size_t)nbuk * cap + BIN_CHUNK) * 8);
    (void)ws_size;

    const int binBlocks  = (E + BIN_CHUNK - 1) / BIN_CHUNK;   // 196
    const int nStripes   = (N + 63) / 64;                     // 1563
    const int gemmBlocks = ((2 * nStripes + 15) / 16) * 16;   // 3136 (x16 groups)

    hipMemsetAsync(cursor, 0, (size_t)nbuk * 4, stream);
    prep_kernel<<<256, 256, 0, stream>>>(W, Wt);
    fused_gemm_bin<<<binBlocks + gemmBlocks, 256, 0, stream>>>(
        feature, Wt, Sb, N, ei, ev, cursor, ecv, E, nbuk, cap, binBlocks);
    sortaccum_kernel<<<nbuk, 512, 0, stream>>>(ecv, cursor, Sb, bias, out, N, cap);
}